// Round 4
// baseline (309.427 us; speedup 1.0000x reference)
//
#include <hip/hip_runtime.h>
#include <math.h>

// ---------------------------------------------------------------------------
// EncoderGPECls: kNN(16) -> PCA curvature blend -> adaptive GPE embeddings
// xyz: [8,4096,3] f32  ->  out: [8,4096,128] f32
//
// R16 = R15 skeleton + 2-queries-per-lane register blocking (ILP not TLP).
//   R15 diagnostic: -15% VALU instr -> 0% time change => latency-bound at
//   ~3 waves/SIMD; neither VALU (~26% true) nor LDS pipe (~38%) saturated.
//   R13/R14 proved more TLP via structure changes loses. So: amortize each
//   broadcast ds_read_b128 over TWO independent med3 ladders (GEMM-style
//   register blocking). ~84 VALU instr per 4-read group => ~336 issue-cycles
//   of independent work hides LDS latency even at 2 waves/SIMD.
//   QPB=128 -> grid 256 (exactly 1 block/CU), LDS = 64K tile + 17.4K arena
//   (sbuf [17][2][512] aliased with 4 x 2-query u16 pub regions) = 82.9KB.
//   Merge tree as R15 for both queries; round 3 is CROSS (4->0 for A,
//   0->4 for B) so the double-precision epilogue runs on waves 0 and 4 in
//   parallel. Csum partials: [b][chunk][2] = 512 entries (R12 reduction).
//   Per-query selection semantics byte-identical to R15's proven path:
//   d2' = 3-fma premultiplied form, sign-flip key encoding, exact tau,
//   SCAP clamp drops latest tie = jax drop, u64 keys lower-index tie-break.
//
// ws float layout:
//   [0, 32768)            curv per point
//   [32768, 131072)       rasig2 (3 SoA planes of 32768)
//   [131072, 131584)      curv partial sums [b][chunk][2] (8 x 32 x 2)
//   [131584, 131680)      per-batch raw sums as 48 DOUBLES
//   [131680, 262752)      repacked points: 8*4096 float4 (-2x,-2y,-2z,|c|^2)
// ---------------------------------------------------------------------------

#define NPTS 4096
#define KNN 17          // 16 neighbors + self (self contributes zero to sums)
#define BLKT 512        // 8 waves; 128 queries per block (2 per lane)
#define QPB 128
#define ESIZE 512       // candidates per wave (eighth)
#define SEG 256         // pass-2 segment size (u8 offsets)
#define SCAP 17         // survivor slots per lane per segment per query

#define WS_CURV  0
#define WS_RAS2  32768
#define WS_CSUM  131072
#define WS_STAT  131584
#define WS_PTS   131680

typedef unsigned long long ull;
#define SENT 0xFFFFFFFFFFFFFFFFULL

// THE single d2' definition: explicit fmaf chain, identical IEEE ops at every
// call site. c = (-2cx,-2cy,-2cz,|c|^2), q = original coords.
// d2'(c,q) = |c|^2 - 2 c.q = |c-q|^2 - |q|^2 (per-query constant offset ->
// identical ordering; can be negative). Self always ranks first.
__device__ __forceinline__ float d2p(float4 c, float qx, float qy, float qz) {
    return __builtin_fmaf(c.x, qx, __builtin_fmaf(c.y, qy,
           __builtin_fmaf(c.z, qz, c.w)));
}

// order-preserving u32 encoding of a (possibly negative) float
__device__ __forceinline__ unsigned encf(float f) {
    unsigned u = __float_as_uint(f);
    return u ^ (unsigned)(((int)u >> 31) | 0x80000000u);
}

// predicated replace-max insert of packed (enc(d2')<<32|idx) key
__device__ __forceinline__ void insertp(ull v, bool ins, ull (&md)[KNN],
                                        ull& maxv, int& maxp) {
#pragma unroll
    for (int k = 0; k < KNN; k++) {
        bool sel = ins && (k == maxp);
        md[k] = sel ? v : md[k];
    }
    maxv = md[0]; maxp = 0;
#pragma unroll
    for (int k = 1; k < KNN; k++) {
        bool g = md[k] > maxv;
        maxv = g ? md[k] : maxv;
        maxp = g ? k : maxp;
    }
}

// ---------------- 3x3 symmetric eigensolve (double, trig method) -----------
__device__ __forceinline__ float curv_from_cov(float c00, float c01, float c02,
                                               float c11, float c12, float c22) {
    double a00 = c00, a01 = c01, a02 = c02, a11 = c11, a12 = c12, a22 = c22;
    double tr = a00 + a11 + a22;
    double q  = tr * (1.0 / 3.0);
    double b00 = a00 - q, b11 = a11 - q, b22 = a22 - q;
    double p2 = b00 * b00 + b11 * b11 + b22 * b22
              + 2.0 * (a01 * a01 + a02 * a02 + a12 * a12);
    double lmin;
    if (p2 < 1e-60) {
        lmin = q;
    } else {
        double p  = sqrt(p2 * (1.0 / 6.0));
        double ip = 1.0 / p;
        double m00 = b00 * ip, m11 = b11 * ip, m22 = b22 * ip;
        double m01 = a01 * ip, m02 = a02 * ip, m12 = a12 * ip;
        double det = m00 * (m11 * m22 - m12 * m12)
                   - m01 * (m01 * m22 - m12 * m02)
                   + m02 * (m01 * m12 - m11 * m02);
        double r = 0.5 * det;
        r = r > 1.0 ? 1.0 : (r < -1.0 ? -1.0 : r);
        double phi = acos(r) * (1.0 / 3.0);
        lmin = q + 2.0 * p * cos(phi + 2.0943951023931953);
    }
    return (float)(lmin / (tr + 1e-6));
}

// ---------------- repack + per-batch raw stats -----------------------------
__global__ void prep_kernel(const float* __restrict__ xyz,
                            float* __restrict__ ws) {
    __shared__ double dstat[48];
    int b = blockIdx.x;
    int tid = threadIdx.x;
    const float* base = xyz + b * NPTS * 3;
    float4* P4 = (float4*)(ws + WS_PTS) + b * NPTS;
    double sx = 0, sy = 0, sz = 0, qxx = 0, qyy = 0, qzz = 0;
    for (int p = tid; p < NPTS; p += BLKT) {
        float x = base[p * 3], y = base[p * 3 + 1], z = base[p * 3 + 2];
        float w = __builtin_fmaf(z, z, __builtin_fmaf(y, y, x * x));
        P4[p] = make_float4(-2.0f * x, -2.0f * y, -2.0f * z, w);
        sx += (double)x; sy += (double)y; sz += (double)z;
        qxx += (double)x * x; qyy += (double)y * y; qzz += (double)z * z;
    }
    for (int off = 32; off > 0; off >>= 1) {
        sx += __shfl_down(sx, off);  sy += __shfl_down(sy, off);
        sz += __shfl_down(sz, off);  qxx += __shfl_down(qxx, off);
        qyy += __shfl_down(qyy, off); qzz += __shfl_down(qzz, off);
    }
    int wid = tid >> 6;
    if ((tid & 63) == 0) {
        dstat[wid * 6 + 0] = sx;  dstat[wid * 6 + 1] = sy;  dstat[wid * 6 + 2] = sz;
        dstat[wid * 6 + 3] = qxx; dstat[wid * 6 + 4] = qyy; dstat[wid * 6 + 5] = qzz;
    }
    __syncthreads();
    if (tid == 0) {
        double* wd = (double*)(ws + WS_STAT);
        for (int qq = 0; qq < 6; qq++) {
            double a = 0.0;
            for (int w = 0; w < 8; w++) a += dstat[w * 6 + qq];
            wd[b * 6 + qq] = a;
        }
    }
}

// ---------------- kNN + covariance + curvature + lstd ----------------------
__global__ __launch_bounds__(BLKT, 2) void knn_kernel(float* __restrict__ ws) {
    __shared__ float4 pts[NPTS];                 // 64 KB (repacked points)
    __shared__ ull aux[2176];                    // 17408 B arena (aliased)
    unsigned char* sbuf = (unsigned char*)aux;   // [SCAP][2][BLKT] u8
    unsigned short* pub = (unsigned short*)aux;  // 4 regions x 2q x 64x17 u16
    int b = blockIdx.x >> 5;                     // 32 blocks per batch
    int chunk = blockIdx.x & 31;
    int tid = threadIdx.x;
    const float4* __restrict__ P4g = (const float4*)(ws + WS_PTS) + b * NPTS;
    for (int p = tid; p < NPTS; p += BLKT) pts[p] = P4g[p];
    __syncthreads();

    int wv = tid >> 6;                           // wave id: candidate eighth
    int lane = tid & 63;
    int iA = chunk * QPB + lane;                 // query A
    int iB = iA + 64;                            // query B
    float4 qcA = pts[iA], qcB = pts[iB];
    float qxA = -0.5f * qcA.x, qyA = -0.5f * qcA.y, qzA = -0.5f * qcA.z;
    float qxB = -0.5f * qcB.x, qyB = -0.5f * qcB.y, qzB = -0.5f * qcB.z;
    int cbase = wv * ESIZE;                      // this wave's candidate range

    // ---- pass 1: two branch-free med3 sorted top-17 ladders ---------------
    float mdA[KNN], mdB[KNN];
#pragma unroll
    for (int k = 0; k < KNN; k++) { mdA[k] = 3.4e38f; mdB[k] = 3.4e38f; }

    float4 cc[4];
#pragma unroll
    for (int u = 0; u < 4; u++) cc[u] = pts[cbase + u];
    for (int m = 0; m < ESIZE; m += 4) {
        float4 cu[4];
#pragma unroll
        for (int u = 0; u < 4; u++) cu[u] = cc[u];
        int mn = (m + 4 < ESIZE) ? (m + 4) : 0;  // last prefetch redundant
#pragma unroll
        for (int u = 0; u < 4; u++) cc[u] = pts[cbase + mn + u];
#pragma unroll
        for (int u = 0; u < 4; u++) {
            float da = d2p(cu[u], qxA, qyA, qzA);
            float db = d2p(cu[u], qxB, qyB, qzB);
#pragma unroll
            for (int k = KNN - 1; k >= 1; k--) { // descending: reads olds only
                mdA[k] = __builtin_amdgcn_fmed3f(da, mdA[k - 1], mdA[k]);
                mdB[k] = __builtin_amdgcn_fmed3f(db, mdB[k - 1], mdB[k]);
            }
            mdA[0] = fminf(da, mdA[0]);
            mdB[0] = fminf(db, mdB[0]);
        }
    }
    float tauA = mdA[KNN - 1];                   // exact 17th, per query
    float tauB = mdB[KNN - 1];

    // ---- pass 2 (2 segments of 256): u8 survivors + exact select, 2 q -----
    ull k17A[KNN], k17B[KNN];
#pragma unroll
    for (int k = 0; k < KNN; k++) { k17A[k] = SENT; k17B[k] = SENT; }
    ull maxvA = SENT, maxvB = SENT; int maxpA = 0, maxpB = 0;

#pragma unroll
    for (int sgi = 0; sgi < 2; sgi++) {
        int segbase = cbase + sgi * SEG;
        int cntA = 0, cntB = 0;
#pragma unroll
        for (int u = 0; u < 4; u++) cc[u] = pts[segbase + u];
        for (int m = 0; m < SEG; m += 4) {
            float4 cu[4];
#pragma unroll
            for (int u = 0; u < 4; u++) cu[u] = cc[u];
            int mn = (m + 4 < SEG) ? (m + 4) : 0;
#pragma unroll
            for (int u = 0; u < 4; u++) cc[u] = pts[segbase + mn + u];
#pragma unroll
            for (int u = 0; u < 4; u++) {
                float da = d2p(cu[u], qxA, qyA, qzA);
                float db = d2p(cu[u], qxB, qyB, qzB);
                if (da <= tauA) {                // clamp drops latest tie = jax
                    if (cntA < SCAP) sbuf[(cntA * 2 + 0) * BLKT + tid] = (unsigned char)(m + u);
                    cntA++;
                }
                if (db <= tauB) {
                    if (cntB < SCAP) sbuf[(cntB * 2 + 1) * BLKT + tid] = (unsigned char)(m + u);
                    cntB++;
                }
            }
        }
        // drain this segment's survivors into the exact u64 top-17s
#pragma unroll
        for (int t = 0; t < SCAP; t++) {
            if (__any(t < cntA)) {
                int ix = segbase + sbuf[(t * 2 + 0) * BLKT + tid];
                float4 c = pts[ix];
                float d2 = d2p(c, qxA, qyA, qzA);
                ull key = ((ull)encf(d2) << 32) | (unsigned)ix;
                bool ins = (t < cntA) && (key < maxvA);
                if (__any(ins)) insertp(key, ins, k17A, maxvA, maxpA);
            }
            if (__any(t < cntB)) {
                int ix = segbase + sbuf[(t * 2 + 1) * BLKT + tid];
                float4 c = pts[ix];
                float d2 = d2p(c, qxB, qyB, qzB);
                ull key = ((ull)encf(d2) << 32) | (unsigned)ix;
                bool ins = (t < cntB) && (key < maxvB);
                if (__any(ins)) insertp(key, ins, k17B, maxvB, maxpB);
            }
        }
    }

    // ---- tournament merge (u16 idx publish, keys rebuilt exactly) ---------
    // region r: pub[r*2176 + q*1088 + lane*17 + k]
    // round 1: 1->0, 3->2, 5->4, 7->6
    __syncthreads();
    if (wv & 1) {
        int r = wv >> 1;
#pragma unroll
        for (int k = 0; k < KNN; k++) {
            pub[r * 2176 + lane * KNN + k]        = (unsigned short)(k17A[k] & 0xffffULL);
            pub[r * 2176 + 1088 + lane * KNN + k] = (unsigned short)(k17B[k] & 0xffffULL);
        }
    }
    __syncthreads();
    if (!(wv & 1)) {
        int r = wv >> 1;
#pragma unroll
        for (int k = 0; k < KNN; k++) {
            int ix = pub[r * 2176 + lane * KNN + k];
            float4 c = pts[ix];
            float d2 = d2p(c, qxA, qyA, qzA);
            ull key = ((ull)encf(d2) << 32) | (unsigned)ix;
            bool ins = key < maxvA;
            if (__any(ins)) insertp(key, ins, k17A, maxvA, maxpA);
        }
#pragma unroll
        for (int k = 0; k < KNN; k++) {
            int ix = pub[r * 2176 + 1088 + lane * KNN + k];
            float4 c = pts[ix];
            float d2 = d2p(c, qxB, qyB, qzB);
            ull key = ((ull)encf(d2) << 32) | (unsigned)ix;
            bool ins = key < maxvB;
            if (__any(ins)) insertp(key, ins, k17B, maxvB, maxpB);
        }
    }
    // round 2: 2->0, 6->4
    __syncthreads();
    if (wv == 2 || wv == 6) {
        int r = wv >> 2;
#pragma unroll
        for (int k = 0; k < KNN; k++) {
            pub[r * 2176 + lane * KNN + k]        = (unsigned short)(k17A[k] & 0xffffULL);
            pub[r * 2176 + 1088 + lane * KNN + k] = (unsigned short)(k17B[k] & 0xffffULL);
        }
    }
    __syncthreads();
    if (wv == 0 || wv == 4) {
        int r = wv >> 2;
#pragma unroll
        for (int k = 0; k < KNN; k++) {
            int ix = pub[r * 2176 + lane * KNN + k];
            float4 c = pts[ix];
            float d2 = d2p(c, qxA, qyA, qzA);
            ull key = ((ull)encf(d2) << 32) | (unsigned)ix;
            bool ins = key < maxvA;
            if (__any(ins)) insertp(key, ins, k17A, maxvA, maxpA);
        }
#pragma unroll
        for (int k = 0; k < KNN; k++) {
            int ix = pub[r * 2176 + 1088 + lane * KNN + k];
            float4 c = pts[ix];
            float d2 = d2p(c, qxB, qyB, qzB);
            ull key = ((ull)encf(d2) << 32) | (unsigned)ix;
            bool ins = key < maxvB;
            if (__any(ins)) insertp(key, ins, k17B, maxvB, maxpB);
        }
    }
    // round 3 (cross): wave4 publishes A -> wave0; wave0 publishes B -> wave4
    __syncthreads();
    if (wv == 4) {
#pragma unroll
        for (int k = 0; k < KNN; k++)
            pub[lane * KNN + k] = (unsigned short)(k17A[k] & 0xffffULL);
    }
    if (wv == 0) {
#pragma unroll
        for (int k = 0; k < KNN; k++)
            pub[2176 + lane * KNN + k] = (unsigned short)(k17B[k] & 0xffffULL);
    }
    __syncthreads();

    // ---- epilogue on waves 0 (query A) and 4 (query B), in parallel -------
    if (wv == 0 || wv == 4) {
        bool isA = (wv == 0);
        // final merge of the opposite half
        float qx = isA ? qxA : qxB, qy = isA ? qyA : qyB, qz = isA ? qzA : qzB;
        ull k17[KNN]; ull maxv; int maxp;
#pragma unroll
        for (int k = 0; k < KNN; k++) k17[k] = isA ? k17A[k] : k17B[k];
        maxv = isA ? maxvA : maxvB; maxp = isA ? maxpA : maxpB;
#pragma unroll
        for (int k = 0; k < KNN; k++) {
            int ix = pub[(isA ? 0 : 2176) + lane * KNN + k];
            float4 c = pts[ix];
            float d2 = d2p(c, qx, qy, qz);
            ull key = ((ull)encf(d2) << 32) | (unsigned)ix;
            bool ins = key < maxv;
            if (__any(ins)) insertp(key, ins, k17, maxv, maxp);
        }

        float s1x = 0, s1y = 0, s1z = 0;
        float cxx = 0, cxy = 0, cxz = 0, cyy = 0, cyz = 0, czz = 0;
#pragma unroll
        for (int k = 0; k < KNN; k++) {
            int j = (int)(k17[k] & 0xffffffffULL);
            float4 c = pts[j];
            float ux = -0.5f * c.x - qx;         // exact original coords
            float uy = -0.5f * c.y - qy;
            float uz = -0.5f * c.z - qz;
            s1x += ux; s1y += uy; s1z += uz;
            cxx += ux * ux; cxy += ux * uy; cxz += ux * uz;
            cyy += uy * uy; cyz += uy * uz; czz += uz * uz;
        }
        const float i16 = 1.0f / 16.0f, i15 = 1.0f / 15.0f;
        float mx = s1x * i16, my = s1y * i16, mz = s1z * i16;
        float c00 = (cxx - 16.0f * mx * mx) * i15;
        float c01 = (cxy - 16.0f * mx * my) * i15;
        float c02 = (cxz - 16.0f * mx * mz) * i15;
        float c11 = (cyy - 16.0f * my * my) * i15;
        float c12 = (cyz - 16.0f * my * mz) * i15;
        float c22 = (czz - 16.0f * mz * mz) * i15;

        float curv = curv_from_cov(c00, c01, c02, c11, c12, c22);

        float v0 = c00 > 0.0f ? c00 : 0.0f;
        float v1 = c11 > 0.0f ? c11 : 0.0f;
        float v2 = c22 > 0.0f ? c22 : 0.0f;
        float r2x = 1.0f / (0.3f * (1.0f + sqrtf(v0)) + 1e-6f);
        float r2y = 1.0f / (0.3f * (1.0f + sqrtf(v1)) + 1e-6f);
        float r2z = 1.0f / (0.3f * (1.0f + sqrtf(v2)) + 1e-6f);

        int g = b * NPTS + (isA ? iA : iB);
        ws[WS_CURV + g] = curv;
        ws[WS_RAS2 + 0 * 32768 + g] = r2x;
        ws[WS_RAS2 + 1 * 32768 + g] = r2y;
        ws[WS_RAS2 + 2 * 32768 + g] = r2z;

        // non-atomic per-(b,chunk,half) partial sum
        float cs = curv;
        for (int off = 32; off > 0; off >>= 1) cs += __shfl_down(cs, off);
        if (lane == 0) ws[WS_CSUM + b * 64 + chunk * 2 + (isA ? 0 : 1)] = cs;
    }
}

// ---------------- final embedding (scalars + cmeans per-block, parallel) ---
__global__ void out_kernel(const float* __restrict__ xyz,
                           const float* __restrict__ ws,
                           float* __restrict__ out) {
    __shared__ float sc[3];                      // rasig1, blend, 1-blend
    __shared__ float scm[8];                     // per-batch curv mean
    if (threadIdx.x < 64) {
        // gstd from double stats (24 lanes) -> sigmoid scalars
        float part = 0.0f;
        if (threadIdx.x < 24) {
            const double* st = (const double*)(ws + WS_STAT);
            int bb = threadIdx.x / 3, dd = threadIdx.x % 3;
            double s = st[bb * 6 + dd], ss = st[bb * 6 + 3 + dd];
            double var = (ss - s * s / 4096.0) / 4095.0;
            part = (float)sqrt(var > 0.0 ? var : 0.0);
        }
        float p2 = part;
        for (int off = 32; off > 0; off >>= 1) p2 += __shfl_down(p2, off);
        if (threadIdx.x == 0) {
            float gf = p2 * (1.0f / 24.0f);
            float denom = 0.3f * (1.0f + gf) + 1e-6f;
            float blend = 1.0f / (1.0f + __expf(-(gf - 0.1f) * 10.0f));
            sc[0] = 1.0f / denom;
            sc[1] = blend;
            sc[2] = 1.0f - blend;
        }
        // per-batch curv means from 512 partials: lane L sums [L*8, L*8+8)
        float cp = 0.0f;
        const float* pf = ws + WS_CSUM;
#pragma unroll
        for (int t = 0; t < 8; t++) cp += pf[threadIdx.x * 8 + t];
        cp += __shfl_down(cp, 4);
        cp += __shfl_down(cp, 2);
        cp += __shfl_down(cp, 1);
        if ((threadIdx.x & 7) == 0) scm[threadIdx.x >> 3] = cp * (1.0f / 4096.0f);
    }
    __syncthreads();

    int idx = blockIdx.x * 256 + (int)threadIdx.x;
    int j = idx & 127;
    int g = idx >> 7;
    int b = g >> 12;
    int f = (j < 127) ? j : 128;                      // OUT_IDX
    int d = (f >= 86) ? 2 : ((f >= 43) ? 1 : 0);
    int t = f - d * 43;
    float fv = (float)((double)(t + 1) * (2.0 / 44.0) - 1.0);  // FEAT_VAL[t]

    float x = xyz[g * 3 + d];
    float rasig1 = sc[0];
    float blend  = sc[1];
    float blendc = sc[2];
    float cmean  = scm[b];
    float curv   = ws[WS_CURV + g];
    float w = 1.0f / (1.0f + __expf(-10.0f * (curv - cmean)));

    float t1 = (x - fv) * rasig1;
    float e1 = blend * __expf(-0.5f * t1 * t1) + blendc * __cosf(t1);
    float t2 = (x - fv) * ws[WS_RAS2 + (d << 15) + g];
    float e2 = __expf(-0.5f * t2 * t2);
    out[idx] = w * e1 + (1.0f - w) * e2;
}

extern "C" void kernel_launch(void* const* d_in, const int* in_sizes, int n_in,
                              void* d_out, int out_size, void* d_ws, size_t ws_size,
                              hipStream_t stream) {
    const float* xyz = (const float*)d_in[0];
    float* out = (float*)d_out;
    float* ws = (float*)d_ws;

    prep_kernel<<<8, BLKT, 0, stream>>>(xyz, ws);
    knn_kernel<<<256, BLKT, 0, stream>>>(ws);
    out_kernel<<<out_size / 256, 256, 0, stream>>>(xyz, ws, out);
}

// Round 5
// 281.071 us; speedup vs baseline: 1.1009x; 1.1009x over previous
//
#include <hip/hip_runtime.h>
#include <math.h>

// ---------------------------------------------------------------------------
// EncoderGPECls: kNN(16) -> PCA curvature blend -> adaptive GPE embeddings
// xyz: [8,4096,3] f32  ->  out: [8,4096,128] f32
//
// R17 = R15's proven per-wave structure at HALF-CLOUD scale for 3 blocks/CU.
//   Evidence R12-R16: true VALU issue ~= waves/SIMD x 11-13% regardless of
//   instruction mix (R15: -15% instr -> 0% time; R16: 2x ILP at half waves
//   -> regression). Lever = resident waves, structure unchanged.
//   Each block stages ONE 32KB half-cloud (2048 pts; no restaging, no extra
//   barriers -- R14's failure was in-loop restaging). LDS = 32K tile + 8.7K
//   arena = 41.5KB -> 3 blocks/CU = 24 waves/CU = 6 waves/SIMD (R15: ~3).
//   Grid 1024 = 8 batches x 64 chunks x 2 halves; per-wave partition = 256
//   candidates; per-partition exact tau + SCAP clamp semantics unchanged.
//   Wave 0 publishes each (query,half)'s exact top-17 u64 keys into d_out
//   (scratch: 8.9MB < 16MB; out_kernel overwrites it afterwards).
//   New merge_kernel: merges the two 17-lists per query (u64 keys embed
//   global per-batch index -> exact jax lower-index tie-break across halves)
//   and runs the moments/eigensolve epilogue, parallelized over 512 waves.
//
// ws float layout:
//   [0, 32768)            curv per point
//   [32768, 131072)       rasig2 (3 SoA planes of 32768)
//   [131072, 131584)      curv partial sums [b][chunk64] (8 x 64)
//   [131584, 131680)      per-batch raw sums as 48 DOUBLES
//   [131680, 262752)      repacked points: 8*4096 float4 (-2x,-2y,-2z,|c|^2)
// d_out scratch (before out_kernel): keys[(b*64+chunk)*2+half][17][64] u64
// ---------------------------------------------------------------------------

#define NPTS 4096
#define KNN 17          // 16 neighbors + self (self contributes zero to sums)
#define BLKT 512        // 8 waves; 64 queries per block (1 per lane)
#define QPB 64
#define HALFN 2048      // points per half-cloud tile (32 KB)
#define PART 256        // candidates per wave partition
#define SCAP 17         // survivor slots per lane

#define WS_CURV  0
#define WS_RAS2  32768
#define WS_CSUM  131072
#define WS_STAT  131584
#define WS_PTS   131680

typedef unsigned long long ull;
#define SENT 0xFFFFFFFFFFFFFFFFULL

// THE single d2' definition: explicit fmaf chain, identical IEEE ops at every
// call site. c = (-2cx,-2cy,-2cz,|c|^2), q = original coords.
// d2'(c,q) = |c|^2 - 2 c.q = |c-q|^2 - |q|^2 (per-query constant offset ->
// identical ordering; can be negative). Self always ranks first.
__device__ __forceinline__ float d2p(float4 c, float qx, float qy, float qz) {
    return __builtin_fmaf(c.x, qx, __builtin_fmaf(c.y, qy,
           __builtin_fmaf(c.z, qz, c.w)));
}

// order-preserving u32 encoding of a (possibly negative) float
__device__ __forceinline__ unsigned encf(float f) {
    unsigned u = __float_as_uint(f);
    return u ^ (unsigned)(((int)u >> 31) | 0x80000000u);
}

// predicated replace-max insert of packed (enc(d2')<<32|idx) key
__device__ __forceinline__ void insertp(ull v, bool ins, ull (&md)[KNN],
                                        ull& maxv, int& maxp) {
#pragma unroll
    for (int k = 0; k < KNN; k++) {
        bool sel = ins && (k == maxp);
        md[k] = sel ? v : md[k];
    }
    maxv = md[0]; maxp = 0;
#pragma unroll
    for (int k = 1; k < KNN; k++) {
        bool g = md[k] > maxv;
        maxv = g ? md[k] : maxv;
        maxp = g ? k : maxp;
    }
}

// ---------------- 3x3 symmetric eigensolve (double, trig method) -----------
__device__ __forceinline__ float curv_from_cov(float c00, float c01, float c02,
                                               float c11, float c12, float c22) {
    double a00 = c00, a01 = c01, a02 = c02, a11 = c11, a12 = c12, a22 = c22;
    double tr = a00 + a11 + a22;
    double q  = tr * (1.0 / 3.0);
    double b00 = a00 - q, b11 = a11 - q, b22 = a22 - q;
    double p2 = b00 * b00 + b11 * b11 + b22 * b22
              + 2.0 * (a01 * a01 + a02 * a02 + a12 * a12);
    double lmin;
    if (p2 < 1e-60) {
        lmin = q;
    } else {
        double p  = sqrt(p2 * (1.0 / 6.0));
        double ip = 1.0 / p;
        double m00 = b00 * ip, m11 = b11 * ip, m22 = b22 * ip;
        double m01 = a01 * ip, m02 = a02 * ip, m12 = a12 * ip;
        double det = m00 * (m11 * m22 - m12 * m12)
                   - m01 * (m01 * m22 - m12 * m02)
                   + m02 * (m01 * m12 - m11 * m02);
        double r = 0.5 * det;
        r = r > 1.0 ? 1.0 : (r < -1.0 ? -1.0 : r);
        double phi = acos(r) * (1.0 / 3.0);
        lmin = q + 2.0 * p * cos(phi + 2.0943951023931953);
    }
    return (float)(lmin / (tr + 1e-6));
}

// ---------------- repack + per-batch raw stats -----------------------------
__global__ void prep_kernel(const float* __restrict__ xyz,
                            float* __restrict__ ws) {
    __shared__ double dstat[48];
    int b = blockIdx.x;
    int tid = threadIdx.x;
    const float* base = xyz + b * NPTS * 3;
    float4* P4 = (float4*)(ws + WS_PTS) + b * NPTS;
    double sx = 0, sy = 0, sz = 0, qxx = 0, qyy = 0, qzz = 0;
    for (int p = tid; p < NPTS; p += BLKT) {
        float x = base[p * 3], y = base[p * 3 + 1], z = base[p * 3 + 2];
        float w = __builtin_fmaf(z, z, __builtin_fmaf(y, y, x * x));
        P4[p] = make_float4(-2.0f * x, -2.0f * y, -2.0f * z, w);
        sx += (double)x; sy += (double)y; sz += (double)z;
        qxx += (double)x * x; qyy += (double)y * y; qzz += (double)z * z;
    }
    for (int off = 32; off > 0; off >>= 1) {
        sx += __shfl_down(sx, off);  sy += __shfl_down(sy, off);
        sz += __shfl_down(sz, off);  qxx += __shfl_down(qxx, off);
        qyy += __shfl_down(qyy, off); qzz += __shfl_down(qzz, off);
    }
    int wid = tid >> 6;
    if ((tid & 63) == 0) {
        dstat[wid * 6 + 0] = sx;  dstat[wid * 6 + 1] = sy;  dstat[wid * 6 + 2] = sz;
        dstat[wid * 6 + 3] = qxx; dstat[wid * 6 + 4] = qyy; dstat[wid * 6 + 5] = qzz;
    }
    __syncthreads();
    if (tid == 0) {
        double* wd = (double*)(ws + WS_STAT);
        for (int qq = 0; qq < 6; qq++) {
            double a = 0.0;
            for (int w = 0; w < 8; w++) a += dstat[w * 6 + qq];
            wd[b * 6 + qq] = a;
        }
    }
}

// ---------------- kNN over one half-cloud: per-(query,half) exact top-17 ---
__global__ __launch_bounds__(BLKT, 6) void knn_kernel(float* __restrict__ ws,
                                                      ull* __restrict__ keys) {
    __shared__ float4 tile[HALFN];               // 32 KB half-cloud
    __shared__ ull aux[1088];                    // 8704 B arena (aliased)
    unsigned char* sbuf = (unsigned char*)aux;   // [SCAP][BLKT] u8 survivors
    unsigned short* pub = (unsigned short*)aux;  // 4 regions x 64x17 u16 idx

    int blk = blockIdx.x;
    int b = blk >> 7;                            // 128 blocks per batch
    int rest = blk & 127;
    int half = rest & 1;
    int chunk = rest >> 1;                       // 64 chunks of 64 queries
    int tid = threadIdx.x;
    const float4* __restrict__ P4g = (const float4*)(ws + WS_PTS) + b * NPTS;
    int hbase = half * HALFN;
    for (int p = tid; p < HALFN; p += BLKT) tile[p] = P4g[hbase + p];
    __syncthreads();

    int wv = tid >> 6;                           // wave id: candidate 1/8th
    int lane = tid & 63;
    int i = chunk * QPB + lane;                  // this lane's query (global)
    float4 qc = P4g[i];                          // query may be in other half
    float qx = -0.5f * qc.x, qy = -0.5f * qc.y, qz = -0.5f * qc.z;  // exact
    int cb = wv * PART;                          // partition base within tile

    // ---- pass 1: branch-free med3 sorted top-17 (values only) -------------
    float md[KNN];
#pragma unroll
    for (int k = 0; k < KNN; k++) md[k] = 3.4e38f;

    float4 cc[4];
#pragma unroll
    for (int u = 0; u < 4; u++) cc[u] = tile[cb + u];
    for (int m = 0; m < PART; m += 4) {
        float4 cu[4];
#pragma unroll
        for (int u = 0; u < 4; u++) cu[u] = cc[u];
        int mn = (m + 4 < PART) ? (m + 4) : 0;   // last prefetch redundant
#pragma unroll
        for (int u = 0; u < 4; u++) cc[u] = tile[cb + mn + u];
#pragma unroll
        for (int u = 0; u < 4; u++) {
            float d2 = d2p(cu[u], qx, qy, qz);
#pragma unroll
            for (int k = KNN - 1; k >= 1; k--)   // descending: reads olds only
                md[k] = __builtin_amdgcn_fmed3f(d2, md[k - 1], md[k]);
            md[0] = fminf(d2, md[0]);
        }
    }
    float tau = md[KNN - 1];   // exact 17th of partition (same chain below)

    // ---- pass 2: u8 survivor offsets (single 256-segment) + exact select --
    ull k17[KNN];
#pragma unroll
    for (int k = 0; k < KNN; k++) k17[k] = SENT;
    ull maxv = SENT; int maxp = 0;
    int cnt = 0;
#pragma unroll
    for (int u = 0; u < 4; u++) cc[u] = tile[cb + u];
    for (int m = 0; m < PART; m += 4) {
        float4 cu[4];
#pragma unroll
        for (int u = 0; u < 4; u++) cu[u] = cc[u];
        int mn = (m + 4 < PART) ? (m + 4) : 0;
#pragma unroll
        for (int u = 0; u < 4; u++) cc[u] = tile[cb + mn + u];
#pragma unroll
        for (int u = 0; u < 4; u++) {
            float d2 = d2p(cu[u], qx, qy, qz);
            if (d2 <= tau) {                     // clamp drops latest tie = jax
                if (cnt < SCAP) sbuf[cnt * BLKT + tid] = (unsigned char)(m + u);
                cnt++;
            }
        }
    }
    // drain survivors into the exact u64 top-17 (keys carry GLOBAL idx)
#pragma unroll
    for (int t = 0; t < SCAP; t++) {
        if (__any(t < cnt)) {
            int off = (int)sbuf[t * BLKT + tid];
            float4 c = tile[cb + off];
            int ix = hbase + cb + off;           // global per-batch index
            float d2 = d2p(c, qx, qy, qz);
            ull key = ((ull)encf(d2) << 32) | (unsigned)ix;
            bool ins = (t < cnt) && (key < maxv);
            if (__any(ins)) insertp(key, ins, k17, maxv, maxp);
        }
    }

    // ---- 3-round tournament merge (u16 idx publish, keys rebuilt exactly) --
    // regions: r * 1088 u16 entries, entry lane*17+k; ix is global per-batch,
    // tile index = ix - hbase (all partitions in this block share the half).
    __syncthreads();
    if (wv & 1) {
#pragma unroll
        for (int k = 0; k < KNN; k++)
            pub[(wv >> 1) * 1088 + lane * KNN + k] = (unsigned short)(k17[k] & 0xffffULL);
    }
    __syncthreads();
    if (!(wv & 1)) {
        int r = wv >> 1;
#pragma unroll
        for (int k = 0; k < KNN; k++) {
            int ix = pub[r * 1088 + lane * KNN + k];
            float4 c = tile[ix - hbase];
            float d2 = d2p(c, qx, qy, qz);
            ull key = ((ull)encf(d2) << 32) | (unsigned)ix;
            bool ins = key < maxv;
            if (__any(ins)) insertp(key, ins, k17, maxv, maxp);
        }
    }
    // round 2: 2->0, 6->4 (regions 0,1)
    __syncthreads();
    if (wv == 2 || wv == 6) {
#pragma unroll
        for (int k = 0; k < KNN; k++)
            pub[(wv >> 2) * 1088 + lane * KNN + k] = (unsigned short)(k17[k] & 0xffffULL);
    }
    __syncthreads();
    if (wv == 0 || wv == 4) {
        int r = wv >> 2;
#pragma unroll
        for (int k = 0; k < KNN; k++) {
            int ix = pub[r * 1088 + lane * KNN + k];
            float4 c = tile[ix - hbase];
            float d2 = d2p(c, qx, qy, qz);
            ull key = ((ull)encf(d2) << 32) | (unsigned)ix;
            bool ins = key < maxv;
            if (__any(ins)) insertp(key, ins, k17, maxv, maxp);
        }
    }
    // round 3: 4->0 (region 0)
    __syncthreads();
    if (wv == 4) {
#pragma unroll
        for (int k = 0; k < KNN; k++)
            pub[lane * KNN + k] = (unsigned short)(k17[k] & 0xffffULL);
    }
    __syncthreads();

    // ---- wave 0: final merge; publish (query,half) top-17 u64 keys --------
    if (wv == 0) {
#pragma unroll
        for (int k = 0; k < KNN; k++) {
            int ix = pub[lane * KNN + k];
            float4 c = tile[ix - hbase];
            float d2 = d2p(c, qx, qy, qz);
            ull key = ((ull)encf(d2) << 32) | (unsigned)ix;
            bool ins = key < maxv;
            if (__any(ins)) insertp(key, ins, k17, maxv, maxp);
        }
        ull* ko = keys + (ull)(((b * 64 + chunk) * 2 + half)) * 1088;
#pragma unroll
        for (int k = 0; k < KNN; k++) ko[k * 64 + lane] = k17[k];  // coalesced
    }
}

// ---------------- merge halves + moments -> curv, rasig2 -------------------
__global__ void merge_kernel(float* __restrict__ ws,
                             const ull* __restrict__ keys) {
    int W = blockIdx.x * 4 + ((int)threadIdx.x >> 6);   // wave id in [0,512)
    int lane = threadIdx.x & 63;
    int b = W >> 6;                                     // batch (W batch-major)
    int q = (W & 63) * QPB + lane;                      // per-batch query idx
    const float4* __restrict__ P4 = (const float4*)(ws + WS_PTS) + b * NPTS;
    float4 qc = P4[q];
    float qx = -0.5f * qc.x, qy = -0.5f * qc.y, qz = -0.5f * qc.z;

    const ull* l0 = keys + (ull)(W * 2) * 1088;         // half 0 list
    ull k17[KNN];
#pragma unroll
    for (int k = 0; k < KNN; k++) k17[k] = l0[k * 64 + lane];
    ull maxv = k17[0]; int maxp = 0;
#pragma unroll
    for (int k = 1; k < KNN; k++) {
        bool g = k17[k] > maxv;
        maxv = g ? k17[k] : maxv;
        maxp = g ? k : maxp;
    }
    const ull* l1 = l0 + 1088;                          // half 1 list
#pragma unroll
    for (int k = 0; k < KNN; k++) {
        ull key = l1[k * 64 + lane];
        bool ins = key < maxv;
        if (__any(ins)) insertp(key, ins, k17, maxv, maxp);
    }

    // ---- moments over the exact global top-17 (incl self: contributes 0) --
    float s1x = 0, s1y = 0, s1z = 0;
    float cxx = 0, cxy = 0, cxz = 0, cyy = 0, cyz = 0, czz = 0;
#pragma unroll
    for (int k = 0; k < KNN; k++) {
        int j = (int)(k17[k] & 0xffffffffULL);
        float4 c = P4[j];                               // L2-resident gather
        float ux = -0.5f * c.x - qx;                    // exact original coords
        float uy = -0.5f * c.y - qy;
        float uz = -0.5f * c.z - qz;
        s1x += ux; s1y += uy; s1z += uz;
        cxx += ux * ux; cxy += ux * uy; cxz += ux * uz;
        cyy += uy * uy; cyz += uy * uz; czz += uz * uz;
    }
    const float i16 = 1.0f / 16.0f, i15 = 1.0f / 15.0f;
    float mx = s1x * i16, my = s1y * i16, mz = s1z * i16;
    float c00 = (cxx - 16.0f * mx * mx) * i15;
    float c01 = (cxy - 16.0f * mx * my) * i15;
    float c02 = (cxz - 16.0f * mx * mz) * i15;
    float c11 = (cyy - 16.0f * my * my) * i15;
    float c12 = (cyz - 16.0f * my * mz) * i15;
    float c22 = (czz - 16.0f * mz * mz) * i15;

    float curv = curv_from_cov(c00, c01, c02, c11, c12, c22);

    float v0 = c00 > 0.0f ? c00 : 0.0f;
    float v1 = c11 > 0.0f ? c11 : 0.0f;
    float v2 = c22 > 0.0f ? c22 : 0.0f;
    float r2x = 1.0f / (0.3f * (1.0f + sqrtf(v0)) + 1e-6f);
    float r2y = 1.0f / (0.3f * (1.0f + sqrtf(v1)) + 1e-6f);
    float r2z = 1.0f / (0.3f * (1.0f + sqrtf(v2)) + 1e-6f);

    int g = b * NPTS + q;
    ws[WS_CURV + g] = curv;
    ws[WS_RAS2 + 0 * 32768 + g] = r2x;
    ws[WS_RAS2 + 1 * 32768 + g] = r2y;
    ws[WS_RAS2 + 2 * 32768 + g] = r2z;

    // non-atomic per-wave partial sum; entry W is batch-major (b = W>>6)
    float cs = curv;
    for (int off = 32; off > 0; off >>= 1) cs += __shfl_down(cs, off);
    if (lane == 0) ws[WS_CSUM + W] = cs;
}

// ---------------- final embedding (scalars + cmeans per-block, parallel) ---
__global__ void out_kernel(const float* __restrict__ xyz,
                           const float* __restrict__ ws,
                           float* __restrict__ out) {
    __shared__ float sc[3];                      // rasig1, blend, 1-blend
    __shared__ float scm[8];                     // per-batch curv mean
    if (threadIdx.x < 64) {
        // gstd from double stats (24 lanes) -> sigmoid scalars
        float part = 0.0f;
        if (threadIdx.x < 24) {
            const double* st = (const double*)(ws + WS_STAT);
            int bb = threadIdx.x / 3, dd = threadIdx.x % 3;
            double s = st[bb * 6 + dd], ss = st[bb * 6 + 3 + dd];
            double var = (ss - s * s / 4096.0) / 4095.0;
            part = (float)sqrt(var > 0.0 ? var : 0.0);
        }
        float p2 = part;
        for (int off = 32; off > 0; off >>= 1) p2 += __shfl_down(p2, off);
        if (threadIdx.x == 0) {
            float gf = p2 * (1.0f / 24.0f);
            float denom = 0.3f * (1.0f + gf) + 1e-6f;
            float blend = 1.0f / (1.0f + __expf(-(gf - 0.1f) * 10.0f));
            sc[0] = 1.0f / denom;
            sc[1] = blend;
            sc[2] = 1.0f - blend;
        }
        // per-batch curv means from 512 partials: lane L sums [L*8, L*8+8)
        float cp = 0.0f;
        const float* pf = ws + WS_CSUM;
#pragma unroll
        for (int t = 0; t < 8; t++) cp += pf[threadIdx.x * 8 + t];
        cp += __shfl_down(cp, 4);
        cp += __shfl_down(cp, 2);
        cp += __shfl_down(cp, 1);
        if ((threadIdx.x & 7) == 0) scm[threadIdx.x >> 3] = cp * (1.0f / 4096.0f);
    }
    __syncthreads();

    int idx = blockIdx.x * 256 + (int)threadIdx.x;
    int j = idx & 127;
    int g = idx >> 7;
    int b = g >> 12;
    int f = (j < 127) ? j : 128;                      // OUT_IDX
    int d = (f >= 86) ? 2 : ((f >= 43) ? 1 : 0);
    int t = f - d * 43;
    float fv = (float)((double)(t + 1) * (2.0 / 44.0) - 1.0);  // FEAT_VAL[t]

    float x = xyz[g * 3 + d];
    float rasig1 = sc[0];
    float blend  = sc[1];
    float blendc = sc[2];
    float cmean  = scm[b];
    float curv   = ws[WS_CURV + g];
    float w = 1.0f / (1.0f + __expf(-10.0f * (curv - cmean)));

    float t1 = (x - fv) * rasig1;
    float e1 = blend * __expf(-0.5f * t1 * t1) + blendc * __cosf(t1);
    float t2 = (x - fv) * ws[WS_RAS2 + (d << 15) + g];
    float e2 = __expf(-0.5f * t2 * t2);
    out[idx] = w * e1 + (1.0f - w) * e2;
}

extern "C" void kernel_launch(void* const* d_in, const int* in_sizes, int n_in,
                              void* d_out, int out_size, void* d_ws, size_t ws_size,
                              hipStream_t stream) {
    const float* xyz = (const float*)d_in[0];
    float* out = (float*)d_out;
    float* ws = (float*)d_ws;
    ull* keys = (ull*)d_out;   // scratch: 8.9MB of the 16MB output buffer;
                               // out_kernel overwrites all of it afterwards.

    prep_kernel<<<8, BLKT, 0, stream>>>(xyz, ws);
    knn_kernel<<<1024, BLKT, 0, stream>>>(ws, keys);
    merge_kernel<<<128, 256, 0, stream>>>(ws, keys);
    out_kernel<<<out_size / 256, 256, 0, stream>>>(xyz, ws, out);
}